// Round 2
// baseline (143634.937 us; speedup 1.0000x reference)
//
#include <hip/hip_runtime.h>
#include <math.h>

#define NN 2048   // 2L
#define LL 1024   // L
#define NSWB 8    // blocked Jacobi sweeps
#define NROUNDS (NSWB * 63)
#define PITER 10  // power iterations for spectral radius
#define JTAU 1e-8f   // relative off^2 threshold (|apq|_rel < 1e-4 -> identity)
#define STREAK_FULL 2016   // 63 rounds x 32 pairs all-skip = one clean sweep

// gctl layout (ints, zeroed at launch): [0]=gconv [1]=streak [2..65]=clean[64]

// ---------------------------------------------------------------------------
__global__ void build_H(const float* __restrict__ hop,  const float* __restrict__ swm,
                        const float* __restrict__ dwm,  const float* __restrict__ hv,
                        const float* __restrict__ sv,   const float* __restrict__ dv,
                        const float* __restrict__ X,    const float* __restrict__ Y,
                        const int*   __restrict__ ivic, const float* __restrict__ sb,
                        const float* __restrict__ gg,   const float* __restrict__ fS,
                        const float* __restrict__ fd,   float* __restrict__ W)
{
    int idx = blockIdx.x * 256 + threadIdx.x;
    int r = idx >> 11, c = idx & (NN - 1);
    float hv0 = hv[0], hv1 = hv[1], sv0 = sv[0], dv0 = dv[0];
    float g0 = gg[0], fS0 = fS[0], fd0 = fd[0];

    float val = 0.f;
    #pragma unroll
    for (int t = 0; t < 2; ++t) {
        int rr = t ? c : r;
        int cc = t ? r : c;
        int e  = rr * NN + cc;
        float v = hv0 * hop[e] - hop[NN*NN + e] + hv1 * hop[2*NN*NN + e]
                + sv0 * swm[e] + dv0 * dwm[e];
        int i = rr & (LL - 1), j = cc & (LL - 1);
        float px = 0.f, py = 0.f;
        float s = sb[i * LL + j];
        int n0 = ivic[i*4+0], n1 = ivic[i*4+1], n2 = ivic[i*4+2], n3 = ivic[i*4+3];
        if (j == n1 || j == n3) px = (X[j] - X[i]) * s;
        if (j == n0 || j == n2) py = (Y[j] - Y[i]) * s;
        float P = px + py, Mm = px - py;
        bool rlo = rr < LL, clo = cc < LL;
        if (rlo && clo)        v += g0 * P;
        else if (!rlo && !clo) v -= g0 * P;
        else                   v += fS0 * P + fd0 * Mm;
        val += 0.5f * v;
    }
    W[idx] = val;
}

// --------------------- power iteration for spectral radius ------------------
__global__ void powv_init(float* v)
{
    int i = blockIdx.x * 256 + threadIdx.x;
    if (i < NN) {
        unsigned h = (unsigned)i * 2654435761u;
        h ^= h >> 13; h *= 2246822519u; h ^= h >> 16;
        v[i] = ((h >> 8) * (1.0f / 16777216.f)) - 0.5f;
    }
}

__global__ void matvec(const float* __restrict__ W, const float* __restrict__ vin,
                       float* __restrict__ vout, double* accslot)
{
    __shared__ float red[256];
    int row = blockIdx.x, tid = threadIdx.x;
    const float* wr = W + (size_t)row * NN;
    float s = 0.f;
    for (int j = tid; j < NN; j += 256) s += wr[j] * vin[j];
    red[tid] = s; __syncthreads();
    for (int off = 128; off; off >>= 1) { if (tid < off) red[tid] += red[tid + off]; __syncthreads(); }
    if (tid == 0) { float y = red[0]; vout[row] = y; atomicAdd(accslot, (double)y * (double)y); }
}

__global__ void add_shift(float* W, const double* acc)
{
    int i = blockIdx.x * 256 + threadIdx.x;
    if (i < NN) {
        double n1 = acc[8 + PITER - 1], n0 = acc[8 + PITER - 2];
        float rho = (float)sqrt(n1 / (n0 > 0.0 ? n0 : 1.0));
        W[(size_t)i * NN + i] += 1.45f * rho;
    }
}

// ------------------- blocked Jacobi: fused persistent kernel ----------------
__device__ __forceinline__ void pair_groups(int pair, int r, int& gp, int& gq)
{
    if (pair == 0) gp = 0;
    else { int t1 = pair - 1 + r; if (t1 >= 63) t1 -= 63; gp = 1 + t1; }
    int t2 = 62 - pair + r; if (t2 >= 63) t2 -= 63; gq = 1 + t2;
}

__device__ __forceinline__ int  agctl_ld(const int* p)
{ return __hip_atomic_load(p, __ATOMIC_RELAXED, __HIP_MEMORY_SCOPE_AGENT); }
__device__ __forceinline__ void agctl_st(int* p, int v)
{ __hip_atomic_store(p, v, __ATOMIC_RELAXED, __HIP_MEMORY_SCOPE_AGENT); }

// grid barrier: monotone counter, agent-scope acq-rel. All 512 blocks are
// co-resident by construction (65.8 KiB LDS/block -> hard cap 2 blocks/CU,
// 2 x 256 CU = 512 = grid), so spinning is deadlock-free.
__device__ __forceinline__ void gridbar(int* bar, int tgt)
{
    __syncthreads();
    if (threadIdx.x == 0) {
        __hip_atomic_fetch_add(bar, 1, __ATOMIC_ACQ_REL, __HIP_MEMORY_SCOPE_AGENT);
        while (__hip_atomic_load(bar, __ATOMIC_ACQUIRE, __HIP_MEMORY_SCOPE_AGENT) < tgt)
            __builtin_amdgcn_s_sleep(1);
    }
    __syncthreads();
}

// One kernel for all NSWB*63 rounds. Per round:
//   A: 512 blocks (32 pairs x 16 chunks) stage W tile -> TT, partial Gram -> Gpart
//   B: blocks 0..31 solve their 64x64 pair (V in registers, fast-math rotations)
//   C: 512 blocks apply W_tile <- TT * V, REUSING TT from phase A (W unchanged
//      between A and C, so no global re-read)
// Convergence: streak of full clean sweeps sets gctl[0]; all blocks break
// uniformly after the phase-B barrier.
__global__ __launch_bounds__(256, 2) void jac_fused(float* __restrict__ W,
                                                    float* __restrict__ Gpart,
                                                    float* __restrict__ Vbuf,
                                                    int* __restrict__ flags,
                                                    int* __restrict__ gctl,
                                                    int* __restrict__ bar)
{
    __shared__ float TT[64][132];   // A/C: 64-col x 128-row W tile
    __shared__ float S[64][65];     // B: pair Gram
    __shared__ float Vs[64][64];    // C: V tile
    __shared__ float csC[32], csS[32];
    __shared__ int   pk[32], qk[32];
    __shared__ int   active;
    __shared__ int   nact[2];

    const int tid   = threadIdx.x;
    const int bid   = blockIdx.x;
    const int gpair = bid >> 4, chunk = bid & 15;   // role in phases A/C
    const int r0    = chunk * 128;
    int sidx = 0;

    for (int rr = 0; rr < NROUNDS; ++rr) {
        int r = rr; while (r >= 63) r -= 63;

        // ---------------- phase A: gram ----------------
        int gp, gq; pair_groups(gpair, r, gp, gq);
        bool apair_clean = (agctl_ld(&gctl[2 + gp]) >= 63 && agctl_ld(&gctl[2 + gq]) >= 63);
        if (!apair_clean) {
            for (int u = tid; u < 64 * 32; u += 256) {
                int c = u >> 5, r4 = (u & 31) << 2;
                int col = (c < 32) ? gp * 32 + c : gq * 32 + (c - 32);
                float4 v = *(const float4*)(W + (size_t)col * NN + r0 + r4);
                *(float4*)&TT[c][r4] = v;
            }
            __syncthreads();
            int ti = tid >> 4, tj = tid & 15;
            float acc[4][4] = {};
            for (int r4 = 0; r4 < 128; r4 += 4) {
                float a[4][4], b[4][4];
                #pragma unroll
                for (int m = 0; m < 4; ++m) *(float4*)a[m] = *(const float4*)&TT[ti + 16*m][r4];
                #pragma unroll
                for (int n = 0; n < 4; ++n) *(float4*)b[n] = *(const float4*)&TT[tj + 16*n][r4];
                #pragma unroll
                for (int m = 0; m < 4; ++m)
                    #pragma unroll
                    for (int n = 0; n < 4; ++n)
                        #pragma unroll
                        for (int k = 0; k < 4; ++k)
                            acc[m][n] += a[m][k] * b[n][k];
            }
            float* gout = Gpart + ((size_t)(gpair << 4) + chunk) * 4096;
            #pragma unroll
            for (int m = 0; m < 4; ++m)
                #pragma unroll
                for (int n = 0; n < 4; ++n)
                    gout[(ti + 16*m) * 64 + (tj + 16*n)] = acc[m][n];
        }
        gridbar(bar, 512 * (++sidx));

        // ---------------- phase B: solve (blocks 0..31) ----------------
        if (bid < 32) {
            int pair = bid;
            int gp2, gq2; pair_groups(pair, r, gp2, gq2);
            int c1 = agctl_ld(&gctl[2 + gp2]);
            int c2 = agctl_ld(&gctl[2 + gq2]);
            if (c1 >= 63 && c2 >= 63) {
                if (tid == 0) {
                    agctl_st(&flags[pair], 1);
                    agctl_st(&gctl[2 + gp2], c1 + 1);   // single writer per group/round
                    agctl_st(&gctl[2 + gq2], c2 + 1);
                    int old = atomicAdd(&gctl[1], 1);
                    if (old + 1 >= STREAK_FULL) agctl_st(&gctl[0], 1);
                }
            } else {
                if (tid == 0) active = 0;
                if (tid < 2) nact[tid] = 0;
                for (int e4 = tid; e4 < 1024; e4 += 256) {
                    float4 s = {0.f, 0.f, 0.f, 0.f};
                    #pragma unroll
                    for (int ch = 0; ch < 16; ++ch) {
                        const float4* gpt = (const float4*)(Gpart + ((size_t)(pair * 16 + ch)) * 4096);
                        float4 v = gpt[e4];
                        s.x += v.x; s.y += v.y; s.z += v.z; s.w += v.w;
                    }
                    int i = e4 >> 4, j0 = (e4 & 15) << 2;
                    S[i][j0] = s.x; S[i][j0+1] = s.y; S[i][j0+2] = s.z; S[i][j0+3] = s.w;
                }
                __syncthreads();
                int loc = 0;
                for (int e = tid; e < 4096; e += 256) {
                    int i = e >> 6, j = e & 63;
                    if (i < j) {
                        float o = S[i][j];
                        if (o * o > JTAU * S[i][i] * S[j][j]) loc = 1;
                    }
                }
                if (loc) active = 1;          // benign race: only ever set to 1
                __syncthreads();
                if (!active) {
                    if (tid == 0) {
                        agctl_st(&flags[pair], 1);
                        agctl_st(&gctl[2 + gp2], c1 + 1);
                        agctl_st(&gctl[2 + gq2], c2 + 1);
                        int old = atomicAdd(&gctl[1], 1);
                        if (old + 1 >= STREAK_FULL) agctl_st(&gctl[0], 1);
                    }
                } else {
                    if (tid == 0) {
                        agctl_st(&flags[pair], 0);
                        agctl_st(&gctl[2 + gp2], 0);
                        agctl_st(&gctl[2 + gq2], 0);
                        atomicExch(&gctl[1], 0);
                    }
                    int lane = tid & 63, wv = tid >> 6;   // 4 waves; wave w owns V rows 16w..16w+15
                    float v[16];
                    #pragma unroll
                    for (int i = 0; i < 16; ++i) v[i] = (16 * wv + i == lane) ? 1.f : 0.f;

                    for (int r2 = 0; r2 < 63; ++r2) {
                        if (tid < 32) {
                            int k = tid, p, q;
                            if (k == 0) p = 0;
                            else { int t1 = k - 1 + r2; if (t1 >= 63) t1 -= 63; p = 1 + t1; }
                            int t2 = 62 - k + r2; if (t2 >= 63) t2 -= 63; q = 1 + t2;
                            float app = S[p][p], aqq = S[q][q], apq = S[p][q];
                            float c = 1.f, s = 0.f;
                            if (apq * apq > JTAU * app * aqq) {
                                // fast-math chain: v_rcp/v_sqrt/v_rsq (~1e-7 rel;
                                // Jacobi is self-correcting and fp32 noise floor is 1e-5)
                                float tau = (aqq - app) * __builtin_amdgcn_rcpf(2.f * apq);
                                float sq  = __builtin_amdgcn_sqrtf(fmaf(tau, tau, 1.f));
                                float t   = (tau >= 0.f ? 1.f : -1.f) *
                                            __builtin_amdgcn_rcpf(fabsf(tau) + sq);
                                c = __builtin_amdgcn_rsqf(fmaf(t, t, 1.f));
                                s = t * c;
                                nact[r2 & 1] = 1;     // benign multi-writer, same value
                            }
                            csC[k] = c; csS[k] = s; pk[k] = p; qk[k] = q;
                        }
                        if (tid == 128) nact[(r2 + 1) & 1] = 0;
                        __syncthreads();
                        if (!nact[r2 & 1]) break;
                        // one-pass S <- J^T S J over disjoint 2x2 blocks (4 units/thread)
                        for (int u = tid; u < 1024; u += 256) {
                            int ki = u >> 5, kj = u & 31;
                            float si_ = csS[ki], sj_ = csS[kj];
                            if (si_ == 0.f && sj_ == 0.f) continue;
                            float ci_ = csC[ki], cj_ = csC[kj];
                            int pi = pk[ki], qi = qk[ki], pj = pk[kj], qj = qk[kj];
                            float a  = S[pi][pj], b  = S[pi][qj];
                            float c2 = S[qi][pj], d  = S[qi][qj];
                            float a1 = cj_ * a  - sj_ * b,  b1 = sj_ * a  + cj_ * b;
                            float c1 = cj_ * c2 - sj_ * d,  d1 = sj_ * c2 + cj_ * d;
                            S[pi][pj] = ci_ * a1 - si_ * c1;
                            S[qi][pj] = si_ * a1 + ci_ * c1;
                            S[pi][qj] = ci_ * b1 - si_ * d1;
                            S[qi][qj] = si_ * b1 + ci_ * d1;
                        }
                        // V <- V * J (register resident: lane = column, shfl p<->q)
                        {
                            int k;
                            if (lane == 0) k = 0;
                            else { int t = lane - 1 - r2; if (t < 0) t += 63;
                                   k = (t <= 30) ? (t + 1) : (62 - t); }
                            float s_ = csS[k];
                            if (s_ != 0.f) {
                                float c_ = csC[k];
                                int p = pk[k], q = qk[k];
                                bool isp = (lane == p);
                                int part = isp ? q : p;
                                #pragma unroll
                                for (int i = 0; i < 16; ++i) {
                                    float other = __shfl(v[i], part);
                                    v[i] = isp ? (c_ * v[i] - s_ * other)
                                               : (s_ * other + c_ * v[i]);
                                }
                            }
                        }
                        __syncthreads();
                    }
                    float* vb = Vbuf + (size_t)pair * 4096 + (size_t)(wv * 16) * 64 + lane;
                    #pragma unroll
                    for (int i = 0; i < 16; ++i) vb[(size_t)i * 64] = v[i];
                }
            }
        }
        gridbar(bar, 512 * (++sidx));

        // ---------------- convergence break (uniform) ----------------
        if (agctl_ld(&gctl[0])) break;

        // ---------------- phase C: apply (reuses TT from phase A) ----------
        if (!agctl_ld(&flags[gpair])) {
            for (int e4 = tid; e4 < 1024; e4 += 256) {
                float4 v = ((const float4*)(Vbuf + (size_t)gpair * 4096))[e4];
                int i = e4 >> 4, j0 = (e4 & 15) << 2;
                Vs[i][j0] = v.x; Vs[i][j0+1] = v.y; Vs[i][j0+2] = v.z; Vs[i][j0+3] = v.w;
            }
            __syncthreads();
            int rt = tid >> 3, ct = tid & 7;
            int rr0 = rt << 2, c20 = ct << 3;
            float acc[4][8] = {};
            for (int c = 0; c < 64; ++c) {
                float a[4], b[8];
                *(float4*)a     = *(const float4*)&TT[c][rr0];
                *(float4*)b     = *(const float4*)&Vs[c][c20];
                *(float4*)&b[4] = *(const float4*)&Vs[c][c20 + 4];
                #pragma unroll
                for (int i = 0; i < 4; ++i)
                    #pragma unroll
                    for (int j = 0; j < 8; ++j)
                        acc[i][j] += a[i] * b[j];
            }
            #pragma unroll
            for (int j = 0; j < 8; ++j) {
                int cc = c20 + j;
                int col = (cc < 32) ? gp * 32 + cc : gq * 32 + (cc - 32);
                float4 v = { acc[0][j], acc[1][j], acc[2][j], acc[3][j] };
                *(float4*)(W + (size_t)col * NN + r0 + rr0) = v;
            }
        }
        gridbar(bar, 512 * (++sidx));
    }
}

// --------------------- norms, selection, gather -----------------------------
__global__ void colnorms(const float* __restrict__ W, float* __restrict__ sig2)
{
    __shared__ float red[256];
    int col = blockIdx.x, tid = threadIdx.x;
    const float* c = W + (size_t)col * NN;
    float s = 0.f;
    for (int e = tid; e < NN; e += 256) s += c[e] * c[e];
    red[tid] = s; __syncthreads();
    for (int off = 128; off; off >>= 1) { if (tid < off) red[tid] += red[tid + off]; __syncthreads(); }
    if (tid == 0) sig2[col] = red[0];
}

__global__ void select_k(const float* __restrict__ sig2, int* __restrict__ sel)
{
    int i = blockIdx.x * 256 + threadIdx.x;
    if (i >= NN) return;
    float di = sig2[i]; int rank = 0;
    for (int j = 0; j < NN; ++j) {
        float dj = sig2[j];
        rank += (dj < di) || (dj == di && j < i);
    }
    if (rank < LL) sel[rank] = i;
}

__global__ void gather_M(const float* __restrict__ W, const float* __restrict__ sig2,
                         const int* __restrict__ sel, const int* __restrict__ occ,
                         float* __restrict__ Mt)
{
    int idx = blockIdx.x * 256 + threadIdx.x;
    int b = idx >> 10, a = idx & (LL - 1);
    int col = sel[b];
    float rn = 1.f / sqrtf(sig2[col]);
    Mt[(size_t)b * LL + a] = W[(size_t)col * NN + occ[a]] * rn;
}

// G = Mt^T * Mt in fp64 (= M M^T)
__global__ void gram(const float* __restrict__ Mt, double* __restrict__ G)
{
    __shared__ float As[32][17], Bs[32][17];
    int t = threadIdx.x;
    int tx = t & 15, ty = t >> 4;
    int a0 = blockIdx.y * 16, c0 = blockIdx.x * 16;
    double s = 0.0;
    for (int kb = 0; kb < LL; kb += 32) {
        for (int u = t; u < 32 * 16; u += 256) {
            int kr = u >> 4, i = u & 15;
            As[kr][i] = Mt[(size_t)(kb + kr) * LL + a0 + i];
            Bs[kr][i] = Mt[(size_t)(kb + kr) * LL + c0 + i];
        }
        __syncthreads();
        #pragma unroll 8
        for (int k2 = 0; k2 < 32; ++k2)
            s += (double)As[k2][ty] * (double)Bs[k2][tx];
        __syncthreads();
    }
    G[(size_t)(a0 + ty) * LL + (c0 + tx)] = s;
}

// --------------------- blocked fp64 Cholesky (panel 64) ---------------------
__global__ void chol_panel(double* __restrict__ G, int k0, double* __restrict__ acc)
{
    __shared__ double Ld[64][65];
    __shared__ double sinv;
    int tid = threadIdx.x;
    for (int u = tid; u < 4096; u += 256)
        Ld[u >> 6][u & 63] = G[(size_t)(k0 + (u >> 6)) * LL + k0 + (u & 63)];
    __syncthreads();
    double lsum = 0.0;
    for (int c = 0; c < 64; ++c) {
        if (tid == 0) {
            double d = Ld[c][c]; d = d > 1e-300 ? d : 1e-300;
            double sd = sqrt(d); lsum += log(sd);
            Ld[c][c] = sd; sinv = 1.0 / sd;
        }
        __syncthreads();
        if (tid < 63 - c) Ld[c + 1 + tid][c] *= sinv;
        __syncthreads();
        for (int u = tid; u < 4096; u += 256) {
            int rr = u >> 6, cc = u & 63;
            if (rr > c && cc > c) Ld[rr][cc] -= Ld[rr][c] * Ld[cc][c];
        }
        __syncthreads();
    }
    for (int u = tid; u < 4096; u += 256)
        G[(size_t)(k0 + (u >> 6)) * LL + k0 + (u & 63)] = Ld[u >> 6][u & 63];
    if (tid == 0) atomicAdd(acc + 1, lsum);
}

__global__ void chol_trsm(double* __restrict__ G, int k0)
{
    __shared__ double L11[64][65];
    __shared__ double Rt[32][65];
    int tid = threadIdx.x;
    int rbase = k0 + 64 + blockIdx.x * 32;
    for (int u = tid; u < 4096; u += 256)
        L11[u >> 6][u & 63] = G[(size_t)(k0 + (u >> 6)) * LL + k0 + (u & 63)];
    for (int u = tid; u < 2048; u += 256)
        Rt[u >> 6][u & 63] = G[(size_t)(rbase + (u >> 6)) * LL + k0 + (u & 63)];
    __syncthreads();
    for (int c = 0; c < 64; ++c) {
        if (tid < 32) Rt[tid][c] *= 1.0 / L11[c][c];
        __syncthreads();
        for (int u = tid; u < 2048; u += 256) {
            int rr = u >> 6, cc = u & 63;
            if (cc > c) Rt[rr][cc] -= Rt[rr][c] * L11[cc][c];
        }
        __syncthreads();
    }
    for (int u = tid; u < 2048; u += 256)
        G[(size_t)(rbase + (u >> 6)) * LL + k0 + (u & 63)] = Rt[u >> 6][u & 63];
}

__global__ void chol_syrk(double* __restrict__ G, int k0)
{
    __shared__ double At[64][32];
    __shared__ double Bt[64][32];
    int tid = threadIdx.x;
    int r0g = k0 + 64 + blockIdx.y * 64;
    int c0g = k0 + 64 + blockIdx.x * 64;
    int i0 = (tid >> 4) << 2, j0 = (tid & 15) << 2;
    double acc[4][4] = {};
    for (int kh = 0; kh < 2; ++kh) {
        for (int u = tid; u < 2048; u += 256) {
            int i = u >> 5, c = u & 31;
            At[i][c] = G[(size_t)(r0g + i) * LL + k0 + kh * 32 + c];
            Bt[i][c] = G[(size_t)(c0g + i) * LL + k0 + kh * 32 + c];
        }
        __syncthreads();
        for (int c = 0; c < 32; ++c) {
            int cr = (c + tid) & 31;
            double a[4], b[4];
            #pragma unroll
            for (int i = 0; i < 4; ++i) a[i] = At[i0 + i][cr];
            #pragma unroll
            for (int j = 0; j < 4; ++j) b[j] = Bt[j0 + j][cr];
            #pragma unroll
            for (int i = 0; i < 4; ++i)
                #pragma unroll
                for (int j = 0; j < 4; ++j)
                    acc[i][j] += a[i] * b[j];
        }
        __syncthreads();
    }
    #pragma unroll
    for (int i = 0; i < 4; ++i)
        #pragma unroll
        for (int j = 0; j < 4; ++j) {
            size_t e = (size_t)(r0g + i0 + i) * LL + c0g + j0 + j;
            G[e] -= acc[i][j];
        }
}

// --------- all O(L^2) circulant quadratic forms + coherent terms ------------
__global__ void pair_sums(const float* __restrict__ Sz,  const float* __restrict__ X,
                          const float* __restrict__ Y,
                          const float* __restrict__ Jsp, const float* __restrict__ JXel,
                          const float* __restrict__ JYel,const float* __restrict__ pXX,
                          const float* __restrict__ pXY, const float* __restrict__ pYY,
                          const float* __restrict__ sb,  const float* __restrict__ stx,
                          const float* __restrict__ sty,
                          const float* __restrict__ zx,  const float* __restrict__ zy,
                          const float* __restrict__ xr,  const float* __restrict__ yr,
                          double* __restrict__ acc)
{
    __shared__ float tS[289], tXe[289], tYe[289], tXX[289], tXY[289], tYY[289];
    __shared__ double red[256];
    int tid = threadIdx.x;
    for (int u = tid; u < 289; u += 256) {
        tS[u]  = (u < 288) ? Jsp[u] : 0.f;
        tXX[u] = (u < 288) ? pXX[u] : 0.f;
        tXY[u] = (u < 288) ? pXY[u] : 0.f;
        tYY[u] = (u < 288) ? pYY[u] : 0.f;
        tXe[u] = (u >= 1 && u < 288) ? JXel[u - 1] : 0.f;
        tYe[u] = (u >= 1 && u < 288) ? JYel[u - 1] : 0.f;
    }
    __syncthreads();
    int idx = blockIdx.x * 256 + tid;
    int i = idx >> 10, j = idx & (LL - 1);
    int xi = i >> 5, yi = i & 31, xj = j >> 5, yj = j & 31;
    int dx = (xj - xi) & 31, dy = (yj - yi) & 31;
    int rx = (dx <= 16) ? dx : 32 - dx;
    int ry = (dy <= 16) ? dy : 32 - dy;
    int ti = rx * 17 + ry;
    float si = Sz[i], sj = Sz[j];
    float Xi = X[i], Xj = X[j], Yi = Y[i], Yj = Y[j];
    float sbij = sb[i * LL + j];
    double sum = (double)(si * sj) * (double)tS[ti];
    sum += (double)(Xi * Xj) * (double)tXX[ti];
    sum += (double)(Yi * Xj + Xi * Yj) * (double)tXY[ti];
    sum += (double)(Yi * Yj) * (double)tYY[ti];
    sum += (double)(si * sj * sbij) *
           ((double)tXe[ti] * (double)(Xi - Xj) + (double)tYe[ti] * (double)(Yi - Yj));
    if (i == j) {
        float ex = Xi - zx[0] * stx[i];
        float ey = Yi - zy[0] * sty[i];
        sum -= 0.5 * (double)xr[0] * ex * ex + 0.5 * (double)yr[0] * ey * ey;
    }
    red[tid] = sum; __syncthreads();
    for (int off = 128; off; off >>= 1) { if (tid < off) red[tid] += red[tid + off]; __syncthreads(); }
    if (tid == 0) atomicAdd(&acc[0], red[0]);
}

__global__ void finalize(const double* __restrict__ acc, float* __restrict__ out)
{
    out[0] = (float)(acc[0] + acc[1]);
}

// ---------------------------------------------------------------------------
extern "C" void kernel_launch(void* const* d_in, const int* in_sizes, int n_in,
                              void* d_out, int out_size, void* d_ws, size_t ws_size,
                              hipStream_t stream)
{
    const int*   occ  = (const int*)  d_in[0];
    const float* Sz   = (const float*)d_in[2];
    const float* X    = (const float*)d_in[3];
    const float* Y    = (const float*)d_in[4];
    const float* hv   = (const float*)d_in[5];
    const float* sv   = (const float*)d_in[6];
    const float* dv   = (const float*)d_in[7];
    const float* Jsp  = (const float*)d_in[8];
    const float* JXel = (const float*)d_in[9];
    const float* JYel = (const float*)d_in[10];
    const float* pXX  = (const float*)d_in[11];
    const float* pXY  = (const float*)d_in[12];
    const float* pYY  = (const float*)d_in[13];
    const float* g    = (const float*)d_in[14];
    const float* fS   = (const float*)d_in[15];
    const float* fd   = (const float*)d_in[16];
    const float* zx   = (const float*)d_in[17];
    const float* zy   = (const float*)d_in[18];
    const float* xr   = (const float*)d_in[19];
    const float* yr   = (const float*)d_in[20];
    const float* hop  = (const float*)d_in[21];
    const float* swm  = (const float*)d_in[22];
    const float* dwm  = (const float*)d_in[23];
    const int*   ivic = (const int*)  d_in[24];
    const float* sb   = (const float*)d_in[25];
    const float* stx  = (const float*)d_in[26];
    const float* sty  = (const float*)d_in[27];
    float* out = (float*)d_out;

    char* ws = (char*)d_ws;
    float*  W    = (float*) (ws + 0);           // 16.78 MB
    float*  v0   = (float*) (ws + 16777216);    // 8 KB
    float*  v1   = (float*) (ws + 16785408);    // 4 KB used
    int*    flags= (int*)   (ws + 16789504);    // 128 B
    float*  sig2 = (float*) (ws + 16793600);
    int*    sel  = (int*)   (ws + 16801792);
    float*  Mt   = (float*) (ws + 16805888);    // 4 MB; first 512KB doubles as Vbuf during Jacobi
    double* G    = (double*)(ws + 21000192);    // 8 MB fp64 Gram; doubles as Gpart (fp32) during Jacobi
    double* acc  = (double*)(ws + 29388800);    // 32 doubles
    int*    gctl = (int*)   (ws + 29389056);    // [0]=gconv [1]=streak [2..65]=clean
    int*    bar  = (int*)   (ws + 29389568);    // grid-barrier counter
    float*  Vbuf  = Mt;
    float*  Gpart = (float*)G;

    hipMemsetAsync(acc, 0, 832, stream);        // zeroes acc + gctl + bar
    build_H<<<NN * NN / 256, 256, 0, stream>>>(hop, swm, dwm, hv, sv, dv, X, Y,
                                               ivic, sb, g, fS, fd, W);
    powv_init<<<8, 256, 0, stream>>>(v0);
    for (int it = 0; it < PITER; ++it) {
        const float* vin = (it & 1) ? v1 : v0;
        float* vout = (it & 1) ? v0 : v1;
        matvec<<<NN, 256, 0, stream>>>(W, vin, vout, acc + 8 + it);
    }
    add_shift<<<8, 256, 0, stream>>>(W, acc);

    // single persistent kernel for all NSWB*63 Jacobi rounds
    jac_fused<<<512, 256, 0, stream>>>(W, Gpart, Vbuf, flags, gctl, bar);

    colnorms<<<NN, 256, 0, stream>>>(W, sig2);
    select_k<<<8, 256, 0, stream>>>(sig2, sel);
    gather_M<<<4096, 256, 0, stream>>>(W, sig2, sel, occ, Mt);
    gram<<<dim3(64, 64), 256, 0, stream>>>(Mt, G);

    for (int s = 0; s < 16; ++s) {
        int k0 = s * 64;
        chol_panel<<<1, 256, 0, stream>>>(G, k0, acc);
        int nrows = LL - k0 - 64;
        if (nrows > 0) {
            chol_trsm<<<nrows / 32, 256, 0, stream>>>(G, k0);
            chol_syrk<<<dim3(nrows / 64, nrows / 64), 256, 0, stream>>>(G, k0);
        }
    }

    pair_sums<<<4096, 256, 0, stream>>>(Sz, X, Y, Jsp, JXel, JYel, pXX, pXY, pYY,
                                        sb, stx, sty, zx, zy, xr, yr, acc);
    finalize<<<1, 1, 0, stream>>>(acc, out);
}

// Round 3
// 87425.562 us; speedup vs baseline: 1.6429x; 1.6429x over previous
//
#include <hip/hip_runtime.h>
#include <math.h>

#define NN 2048   // 2L
#define LL 1024   // L
#define NSWB 8    // blocked Jacobi sweeps
#define NROUNDS (NSWB * 63)
#define PITER 10  // power iterations for spectral radius
#define JTAU 1e-8f   // relative off^2 threshold (|apq|_rel < 1e-4 -> identity)
#define STREAK_FULL 2016   // 63 rounds x 32 pairs all-skip = one clean sweep

// gctl layout (ints, zeroed at launch): [0]=gconv [1]=streak [2..65]=clean[64]

// ---------------------------------------------------------------------------
__global__ void build_H(const float* __restrict__ hop,  const float* __restrict__ swm,
                        const float* __restrict__ dwm,  const float* __restrict__ hv,
                        const float* __restrict__ sv,   const float* __restrict__ dv,
                        const float* __restrict__ X,    const float* __restrict__ Y,
                        const int*   __restrict__ ivic, const float* __restrict__ sb,
                        const float* __restrict__ gg,   const float* __restrict__ fS,
                        const float* __restrict__ fd,   float* __restrict__ W)
{
    int idx = blockIdx.x * 256 + threadIdx.x;
    int r = idx >> 11, c = idx & (NN - 1);
    float hv0 = hv[0], hv1 = hv[1], sv0 = sv[0], dv0 = dv[0];
    float g0 = gg[0], fS0 = fS[0], fd0 = fd[0];

    float val = 0.f;
    #pragma unroll
    for (int t = 0; t < 2; ++t) {
        int rr = t ? c : r;
        int cc = t ? r : c;
        int e  = rr * NN + cc;
        float v = hv0 * hop[e] - hop[NN*NN + e] + hv1 * hop[2*NN*NN + e]
                + sv0 * swm[e] + dv0 * dwm[e];
        int i = rr & (LL - 1), j = cc & (LL - 1);
        float px = 0.f, py = 0.f;
        float s = sb[i * LL + j];
        int n0 = ivic[i*4+0], n1 = ivic[i*4+1], n2 = ivic[i*4+2], n3 = ivic[i*4+3];
        if (j == n1 || j == n3) px = (X[j] - X[i]) * s;
        if (j == n0 || j == n2) py = (Y[j] - Y[i]) * s;
        float P = px + py, Mm = px - py;
        bool rlo = rr < LL, clo = cc < LL;
        if (rlo && clo)        v += g0 * P;
        else if (!rlo && !clo) v -= g0 * P;
        else                   v += fS0 * P + fd0 * Mm;
        val += 0.5f * v;
    }
    W[idx] = val;
}

// --------------------- power iteration for spectral radius ------------------
__global__ void powv_init(float* v)
{
    int i = blockIdx.x * 256 + threadIdx.x;
    if (i < NN) {
        unsigned h = (unsigned)i * 2654435761u;
        h ^= h >> 13; h *= 2246822519u; h ^= h >> 16;
        v[i] = ((h >> 8) * (1.0f / 16777216.f)) - 0.5f;
    }
}

__global__ void matvec(const float* __restrict__ W, const float* __restrict__ vin,
                       float* __restrict__ vout, double* accslot)
{
    __shared__ float red[256];
    int row = blockIdx.x, tid = threadIdx.x;
    const float* wr = W + (size_t)row * NN;
    float s = 0.f;
    for (int j = tid; j < NN; j += 256) s += wr[j] * vin[j];
    red[tid] = s; __syncthreads();
    for (int off = 128; off; off >>= 1) { if (tid < off) red[tid] += red[tid + off]; __syncthreads(); }
    if (tid == 0) { float y = red[0]; vout[row] = y; atomicAdd(accslot, (double)y * (double)y); }
}

__global__ void add_shift(float* W, const double* acc)
{
    int i = blockIdx.x * 256 + threadIdx.x;
    if (i < NN) {
        double n1 = acc[8 + PITER - 1], n0 = acc[8 + PITER - 2];
        float rho = (float)sqrt(n1 / (n0 > 0.0 ? n0 : 1.0));
        W[(size_t)i * NN + i] += 1.45f * rho;
    }
}

// ------------------- blocked Jacobi: fused persistent kernel ----------------
__device__ __forceinline__ void pair_groups(int pair, int r, int& gp, int& gq)
{
    if (pair == 0) gp = 0;
    else { int t1 = pair - 1 + r; if (t1 >= 63) t1 -= 63; gp = 1 + t1; }
    int t2 = 62 - pair + r; if (t2 >= 63) t2 -= 63; gq = 1 + t2;
}

__device__ __forceinline__ int  agctl_ld(const int* p)
{ return __hip_atomic_load(p, __ATOMIC_RELAXED, __HIP_MEMORY_SCOPE_AGENT); }
__device__ __forceinline__ void agctl_st(int* p, int v)
{ __hip_atomic_store(p, v, __ATOMIC_RELAXED, __HIP_MEMORY_SCOPE_AGENT); }

// Two-level tree barrier, monotone epochs.
// bars[g*32], g=0..7 : sub-counter for the 64 blocks with (bid&7)==g.
//   Blocks dispatch round-robin across the 8 XCDs, so each sub-counter's
//   line stays in one XCD's L2 -> arrivals are local (~50ns), not the
//   512-way cross-XCD line-bounce (~200ns each = 106us) that killed v1.
// bars[8*32] : top counter (8 leaders/phase). bars[9*32] : epoch word.
// Release-sequence chain: arrival RMW(acq_rel) -> leader RMW(acq_rel) ->
// epoch store(release); waiters spin RELAXED then one ACQUIRE load.
__device__ __forceinline__ void gridbar(int* bars, int phase)
{
    __syncthreads();
    if (threadIdx.x == 0) {
        int g = blockIdx.x & 7;
        int old = __hip_atomic_fetch_add(&bars[g * 32], 1,
                      __ATOMIC_ACQ_REL, __HIP_MEMORY_SCOPE_AGENT);
        if (old == phase * 64 - 1) {                       // group leader
            int t = __hip_atomic_fetch_add(&bars[8 * 32], 1,
                        __ATOMIC_ACQ_REL, __HIP_MEMORY_SCOPE_AGENT);
            if (t == phase * 8 - 1)                        // global last
                __hip_atomic_store(&bars[9 * 32], phase,
                    __ATOMIC_RELEASE, __HIP_MEMORY_SCOPE_AGENT);
        }
        while (__hip_atomic_load(&bars[9 * 32], __ATOMIC_RELAXED,
                   __HIP_MEMORY_SCOPE_AGENT) < phase)
            __builtin_amdgcn_s_sleep(8);
        (void)__hip_atomic_load(&bars[9 * 32], __ATOMIC_ACQUIRE,
                   __HIP_MEMORY_SCOPE_AGENT);
    }
    __syncthreads();
}

// One kernel for all NSWB*63 rounds, 512 blocks x 512 threads (2 blocks/CU by
// LDS capacity -> all co-resident). Per round:
//   A: 512 blocks (32 pairs x 16 chunks) stage W tile -> TT, partial Gram -> Gpart
//   B: blocks 0..31 solve their 64x64 pair (V in registers, fast-math rotations)
//   C: 512 blocks apply W_tile <- TT * V, reusing TT from phase A
__global__ __launch_bounds__(512, 4) void jac_fused(float* __restrict__ W,
                                                    float* __restrict__ Gpart,
                                                    float* __restrict__ Vbuf,
                                                    int* __restrict__ flags,
                                                    int* __restrict__ gctl,
                                                    int* __restrict__ bars)
{
    __shared__ float TT[64][132];   // A/C: 64-col x 128-row W tile
    __shared__ float S[64][65];     // B: pair Gram
    __shared__ float Vs[64][64];    // C: V tile
    __shared__ float csC[32], csS[32];
    __shared__ int   pk[32], qk[32];
    __shared__ int   active;
    __shared__ int   nact[2];

    const int tid   = threadIdx.x;
    const int bid   = blockIdx.x;
    const int gpair = bid >> 4, chunk = bid & 15;   // role in phases A/C
    const int r0    = chunk * 128;
    int sidx = 0;

    for (int rr = 0; rr < NROUNDS; ++rr) {
        int r = rr; while (r >= 63) r -= 63;

        // ---------------- phase A: gram ----------------
        int gp, gq; pair_groups(gpair, r, gp, gq);
        bool apair_clean = (agctl_ld(&gctl[2 + gp]) >= 63 && agctl_ld(&gctl[2 + gq]) >= 63);
        if (!apair_clean) {
            for (int u = tid; u < 64 * 32; u += 512) {
                int c = u >> 5, r4 = (u & 31) << 2;
                int col = (c < 32) ? gp * 32 + c : gq * 32 + (c - 32);
                float4 v = *(const float4*)(W + (size_t)col * NN + r0 + r4);
                *(float4*)&TT[c][r4] = v;
            }
            __syncthreads();
            // 16x32 thread grid: rows {tr+16m} (4), cols {tc+32n} (2)
            int tr = tid & 15, tc = tid >> 4;
            float acc[4][2] = {};
            for (int r4 = 0; r4 < 128; r4 += 4) {
                float a[4][4], b[2][4];
                #pragma unroll
                for (int m = 0; m < 4; ++m) *(float4*)a[m] = *(const float4*)&TT[tr + 16*m][r4];
                #pragma unroll
                for (int n = 0; n < 2; ++n) *(float4*)b[n] = *(const float4*)&TT[tc + 32*n][r4];
                #pragma unroll
                for (int m = 0; m < 4; ++m)
                    #pragma unroll
                    for (int n = 0; n < 2; ++n)
                        #pragma unroll
                        for (int k = 0; k < 4; ++k)
                            acc[m][n] += a[m][k] * b[n][k];
            }
            float* gout = Gpart + ((size_t)(gpair << 4) + chunk) * 4096;
            #pragma unroll
            for (int m = 0; m < 4; ++m)
                #pragma unroll
                for (int n = 0; n < 2; ++n)
                    gout[(tr + 16*m) * 64 + (tc + 32*n)] = acc[m][n];
        }
        gridbar(bars, ++sidx);

        // ---------------- phase B: solve (blocks 0..31) ----------------
        if (bid < 32) {
            int pair = bid;
            int gp2, gq2; pair_groups(pair, r, gp2, gq2);
            int c1 = agctl_ld(&gctl[2 + gp2]);
            int c2 = agctl_ld(&gctl[2 + gq2]);
            if (c1 >= 63 && c2 >= 63) {
                if (tid == 0) {
                    agctl_st(&flags[pair], 1);
                    agctl_st(&gctl[2 + gp2], c1 + 1);   // single writer per group/round
                    agctl_st(&gctl[2 + gq2], c2 + 1);
                    int old = atomicAdd(&gctl[1], 1);
                    if (old + 1 >= STREAK_FULL) agctl_st(&gctl[0], 1);
                }
            } else {
                if (tid == 0) active = 0;
                if (tid < 2) nact[tid] = 0;
                for (int e4 = tid; e4 < 1024; e4 += 512) {
                    float4 s = {0.f, 0.f, 0.f, 0.f};
                    #pragma unroll
                    for (int ch = 0; ch < 16; ++ch) {
                        const float4* gpt = (const float4*)(Gpart + ((size_t)(pair * 16 + ch)) * 4096);
                        float4 v = gpt[e4];
                        s.x += v.x; s.y += v.y; s.z += v.z; s.w += v.w;
                    }
                    int i = e4 >> 4, j0 = (e4 & 15) << 2;
                    S[i][j0] = s.x; S[i][j0+1] = s.y; S[i][j0+2] = s.z; S[i][j0+3] = s.w;
                }
                __syncthreads();
                int loc = 0;
                for (int e = tid; e < 4096; e += 512) {
                    int i = e >> 6, j = e & 63;
                    if (i < j) {
                        float o = S[i][j];
                        if (o * o > JTAU * S[i][i] * S[j][j]) loc = 1;
                    }
                }
                if (loc) active = 1;          // benign race: only ever set to 1
                __syncthreads();
                if (!active) {
                    if (tid == 0) {
                        agctl_st(&flags[pair], 1);
                        agctl_st(&gctl[2 + gp2], c1 + 1);
                        agctl_st(&gctl[2 + gq2], c2 + 1);
                        int old = atomicAdd(&gctl[1], 1);
                        if (old + 1 >= STREAK_FULL) agctl_st(&gctl[0], 1);
                    }
                } else {
                    if (tid == 0) {
                        agctl_st(&flags[pair], 0);
                        agctl_st(&gctl[2 + gp2], 0);
                        agctl_st(&gctl[2 + gq2], 0);
                        atomicExch(&gctl[1], 0);
                    }
                    int lane = tid & 63, wv = tid >> 6;   // 8 waves; wave w owns V rows 8w..8w+7
                    float v[8];
                    #pragma unroll
                    for (int i = 0; i < 8; ++i) v[i] = (8 * wv + i == lane) ? 1.f : 0.f;

                    for (int r2 = 0; r2 < 63; ++r2) {
                        if (tid < 32) {
                            int k = tid, p, q;
                            if (k == 0) p = 0;
                            else { int t1 = k - 1 + r2; if (t1 >= 63) t1 -= 63; p = 1 + t1; }
                            int t2 = 62 - k + r2; if (t2 >= 63) t2 -= 63; q = 1 + t2;
                            float app = S[p][p], aqq = S[q][q], apq = S[p][q];
                            float c = 1.f, s = 0.f;
                            if (apq * apq > JTAU * app * aqq) {
                                // fast-math chain (~1e-7 rel; Jacobi self-corrects,
                                // fp32 noise floor is 1e-5)
                                float tau = (aqq - app) * __builtin_amdgcn_rcpf(2.f * apq);
                                float sq  = __builtin_amdgcn_sqrtf(fmaf(tau, tau, 1.f));
                                float t   = (tau >= 0.f ? 1.f : -1.f) *
                                            __builtin_amdgcn_rcpf(fabsf(tau) + sq);
                                c = __builtin_amdgcn_rsqf(fmaf(t, t, 1.f));
                                s = t * c;
                                nact[r2 & 1] = 1;     // benign multi-writer, same value
                            }
                            csC[k] = c; csS[k] = s; pk[k] = p; qk[k] = q;
                        }
                        if (tid == 256) nact[(r2 + 1) & 1] = 0;
                        __syncthreads();
                        if (!nact[r2 & 1]) break;
                        // one-pass S <- J^T S J over disjoint 2x2 blocks (2/thread)
                        for (int u = tid; u < 1024; u += 512) {
                            int ki = u >> 5, kj = u & 31;
                            float si_ = csS[ki], sj_ = csS[kj];
                            if (si_ == 0.f && sj_ == 0.f) continue;
                            float ci_ = csC[ki], cj_ = csC[kj];
                            int pi = pk[ki], qi = qk[ki], pj = pk[kj], qj = qk[kj];
                            float a  = S[pi][pj], b  = S[pi][qj];
                            float c2 = S[qi][pj], d  = S[qi][qj];
                            float a1 = cj_ * a  - sj_ * b,  b1 = sj_ * a  + cj_ * b;
                            float c1 = cj_ * c2 - sj_ * d,  d1 = sj_ * c2 + cj_ * d;
                            S[pi][pj] = ci_ * a1 - si_ * c1;
                            S[qi][pj] = si_ * a1 + ci_ * c1;
                            S[pi][qj] = ci_ * b1 - si_ * d1;
                            S[qi][qj] = si_ * b1 + ci_ * d1;
                        }
                        // V <- V * J (register resident: lane = column, shfl p<->q)
                        {
                            int k;
                            if (lane == 0) k = 0;
                            else { int t = lane - 1 - r2; if (t < 0) t += 63;
                                   k = (t <= 30) ? (t + 1) : (62 - t); }
                            float s_ = csS[k];
                            if (s_ != 0.f) {
                                float c_ = csC[k];
                                int p = pk[k], q = qk[k];
                                bool isp = (lane == p);
                                int part = isp ? q : p;
                                #pragma unroll
                                for (int i = 0; i < 8; ++i) {
                                    float other = __shfl(v[i], part);
                                    v[i] = isp ? (c_ * v[i] - s_ * other)
                                               : (s_ * other + c_ * v[i]);
                                }
                            }
                        }
                        __syncthreads();
                    }
                    float* vb = Vbuf + (size_t)pair * 4096 + (size_t)(wv * 8) * 64 + lane;
                    #pragma unroll
                    for (int i = 0; i < 8; ++i) vb[(size_t)i * 64] = v[i];
                }
            }
        }
        gridbar(bars, ++sidx);

        // ---------------- convergence break (uniform) ----------------
        if (agctl_ld(&gctl[0])) break;

        // ---------------- phase C: apply (reuses TT from phase A) ----------
        if (!agctl_ld(&flags[gpair])) {
            for (int e4 = tid; e4 < 1024; e4 += 512) {
                float4 v = ((const float4*)(Vbuf + (size_t)gpair * 4096))[e4];
                int i = e4 >> 4, j0 = (e4 & 15) << 2;
                Vs[i][j0] = v.x; Vs[i][j0+1] = v.y; Vs[i][j0+2] = v.z; Vs[i][j0+3] = v.w;
            }
            __syncthreads();
            // 32x16 thread grid: rows rr0..rr0+3 (128), cols c20..c20+3 (64)
            int rt = tid >> 4, ct = tid & 15;
            int rr0 = rt << 2, c20 = ct << 2;
            float acc[4][4] = {};
            for (int c = 0; c < 64; ++c) {
                float a[4], b[4];
                *(float4*)a = *(const float4*)&TT[c][rr0];
                *(float4*)b = *(const float4*)&Vs[c][c20];
                #pragma unroll
                for (int i = 0; i < 4; ++i)
                    #pragma unroll
                    for (int j = 0; j < 4; ++j)
                        acc[i][j] += a[i] * b[j];
            }
            #pragma unroll
            for (int j = 0; j < 4; ++j) {
                int cc = c20 + j;
                int col = (cc < 32) ? gp * 32 + cc : gq * 32 + (cc - 32);
                float4 v = { acc[0][j], acc[1][j], acc[2][j], acc[3][j] };
                *(float4*)(W + (size_t)col * NN + r0 + rr0) = v;
            }
        }
        gridbar(bars, ++sidx);
    }
}

// --------------------- norms, selection, gather -----------------------------
__global__ void colnorms(const float* __restrict__ W, float* __restrict__ sig2)
{
    __shared__ float red[256];
    int col = blockIdx.x, tid = threadIdx.x;
    const float* c = W + (size_t)col * NN;
    float s = 0.f;
    for (int e = tid; e < NN; e += 256) s += c[e] * c[e];
    red[tid] = s; __syncthreads();
    for (int off = 128; off; off >>= 1) { if (tid < off) red[tid] += red[tid + off]; __syncthreads(); }
    if (tid == 0) sig2[col] = red[0];
}

__global__ void select_k(const float* __restrict__ sig2, int* __restrict__ sel)
{
    int i = blockIdx.x * 256 + threadIdx.x;
    if (i >= NN) return;
    float di = sig2[i]; int rank = 0;
    for (int j = 0; j < NN; ++j) {
        float dj = sig2[j];
        rank += (dj < di) || (dj == di && j < i);
    }
    if (rank < LL) sel[rank] = i;
}

__global__ void gather_M(const float* __restrict__ W, const float* __restrict__ sig2,
                         const int* __restrict__ sel, const int* __restrict__ occ,
                         float* __restrict__ Mt)
{
    int idx = blockIdx.x * 256 + threadIdx.x;
    int b = idx >> 10, a = idx & (LL - 1);
    int col = sel[b];
    float rn = 1.f / sqrtf(sig2[col]);
    Mt[(size_t)b * LL + a] = W[(size_t)col * NN + occ[a]] * rn;
}

// G = Mt^T * Mt in fp64 (= M M^T)
__global__ void gram(const float* __restrict__ Mt, double* __restrict__ G)
{
    __shared__ float As[32][17], Bs[32][17];
    int t = threadIdx.x;
    int tx = t & 15, ty = t >> 4;
    int a0 = blockIdx.y * 16, c0 = blockIdx.x * 16;
    double s = 0.0;
    for (int kb = 0; kb < LL; kb += 32) {
        for (int u = t; u < 32 * 16; u += 256) {
            int kr = u >> 4, i = u & 15;
            As[kr][i] = Mt[(size_t)(kb + kr) * LL + a0 + i];
            Bs[kr][i] = Mt[(size_t)(kb + kr) * LL + c0 + i];
        }
        __syncthreads();
        #pragma unroll 8
        for (int k2 = 0; k2 < 32; ++k2)
            s += (double)As[k2][ty] * (double)Bs[k2][tx];
        __syncthreads();
    }
    G[(size_t)(a0 + ty) * LL + (c0 + tx)] = s;
}

// --------------------- blocked fp64 Cholesky (panel 64) ---------------------
__global__ void chol_panel(double* __restrict__ G, int k0, double* __restrict__ acc)
{
    __shared__ double Ld[64][65];
    __shared__ double sinv;
    int tid = threadIdx.x;
    for (int u = tid; u < 4096; u += 256)
        Ld[u >> 6][u & 63] = G[(size_t)(k0 + (u >> 6)) * LL + k0 + (u & 63)];
    __syncthreads();
    double lsum = 0.0;
    for (int c = 0; c < 64; ++c) {
        if (tid == 0) {
            double d = Ld[c][c]; d = d > 1e-300 ? d : 1e-300;
            double sd = sqrt(d); lsum += log(sd);
            Ld[c][c] = sd; sinv = 1.0 / sd;
        }
        __syncthreads();
        if (tid < 63 - c) Ld[c + 1 + tid][c] *= sinv;
        __syncthreads();
        for (int u = tid; u < 4096; u += 256) {
            int rr = u >> 6, cc = u & 63;
            if (rr > c && cc > c) Ld[rr][cc] -= Ld[rr][c] * Ld[cc][c];
        }
        __syncthreads();
    }
    for (int u = tid; u < 4096; u += 256)
        G[(size_t)(k0 + (u >> 6)) * LL + k0 + (u & 63)] = Ld[u >> 6][u & 63];
    if (tid == 0) atomicAdd(acc + 1, lsum);
}

__global__ void chol_trsm(double* __restrict__ G, int k0)
{
    __shared__ double L11[64][65];
    __shared__ double Rt[32][65];
    int tid = threadIdx.x;
    int rbase = k0 + 64 + blockIdx.x * 32;
    for (int u = tid; u < 4096; u += 256)
        L11[u >> 6][u & 63] = G[(size_t)(k0 + (u >> 6)) * LL + k0 + (u & 63)];
    for (int u = tid; u < 2048; u += 256)
        Rt[u >> 6][u & 63] = G[(size_t)(rbase + (u >> 6)) * LL + k0 + (u & 63)];
    __syncthreads();
    for (int c = 0; c < 64; ++c) {
        if (tid < 32) Rt[tid][c] *= 1.0 / L11[c][c];
        __syncthreads();
        for (int u = tid; u < 2048; u += 256) {
            int rr = u >> 6, cc = u & 63;
            if (cc > c) Rt[rr][cc] -= Rt[rr][c] * L11[cc][c];
        }
        __syncthreads();
    }
    for (int u = tid; u < 2048; u += 256)
        G[(size_t)(rbase + (u >> 6)) * LL + k0 + (u & 63)] = Rt[u >> 6][u & 63];
}

__global__ void chol_syrk(double* __restrict__ G, int k0)
{
    __shared__ double At[64][32];
    __shared__ double Bt[64][32];
    int tid = threadIdx.x;
    int r0g = k0 + 64 + blockIdx.y * 64;
    int c0g = k0 + 64 + blockIdx.x * 64;
    int i0 = (tid >> 4) << 2, j0 = (tid & 15) << 2;
    double acc[4][4] = {};
    for (int kh = 0; kh < 2; ++kh) {
        for (int u = tid; u < 2048; u += 256) {
            int i = u >> 5, c = u & 31;
            At[i][c] = G[(size_t)(r0g + i) * LL + k0 + kh * 32 + c];
            Bt[i][c] = G[(size_t)(c0g + i) * LL + k0 + kh * 32 + c];
        }
        __syncthreads();
        for (int c = 0; c < 32; ++c) {
            int cr = (c + tid) & 31;
            double a[4], b[4];
            #pragma unroll
            for (int i = 0; i < 4; ++i) a[i] = At[i0 + i][cr];
            #pragma unroll
            for (int j = 0; j < 4; ++j) b[j] = Bt[j0 + j][cr];
            #pragma unroll
            for (int i = 0; i < 4; ++i)
                #pragma unroll
                for (int j = 0; j < 4; ++j)
                    acc[i][j] += a[i] * b[j];
        }
        __syncthreads();
    }
    #pragma unroll
    for (int i = 0; i < 4; ++i)
        #pragma unroll
        for (int j = 0; j < 4; ++j) {
            size_t e = (size_t)(r0g + i0 + i) * LL + c0g + j0 + j;
            G[e] -= acc[i][j];
        }
}

// --------- all O(L^2) circulant quadratic forms + coherent terms ------------
__global__ void pair_sums(const float* __restrict__ Sz,  const float* __restrict__ X,
                          const float* __restrict__ Y,
                          const float* __restrict__ Jsp, const float* __restrict__ JXel,
                          const float* __restrict__ JYel,const float* __restrict__ pXX,
                          const float* __restrict__ pXY, const float* __restrict__ pYY,
                          const float* __restrict__ sb,  const float* __restrict__ stx,
                          const float* __restrict__ sty,
                          const float* __restrict__ zx,  const float* __restrict__ zy,
                          const float* __restrict__ xr,  const float* __restrict__ yr,
                          double* __restrict__ acc)
{
    __shared__ float tS[289], tXe[289], tYe[289], tXX[289], tXY[289], tYY[289];
    __shared__ double red[256];
    int tid = threadIdx.x;
    for (int u = tid; u < 289; u += 256) {
        tS[u]  = (u < 288) ? Jsp[u] : 0.f;
        tXX[u] = (u < 288) ? pXX[u] : 0.f;
        tXY[u] = (u < 288) ? pXY[u] : 0.f;
        tYY[u] = (u < 288) ? pYY[u] : 0.f;
        tXe[u] = (u >= 1 && u < 288) ? JXel[u - 1] : 0.f;
        tYe[u] = (u >= 1 && u < 288) ? JYel[u - 1] : 0.f;
    }
    __syncthreads();
    int idx = blockIdx.x * 256 + tid;
    int i = idx >> 10, j = idx & (LL - 1);
    int xi = i >> 5, yi = i & 31, xj = j >> 5, yj = j & 31;
    int dx = (xj - xi) & 31, dy = (yj - yi) & 31;
    int rx = (dx <= 16) ? dx : 32 - dx;
    int ry = (dy <= 16) ? dy : 32 - dy;
    int ti = rx * 17 + ry;
    float si = Sz[i], sj = Sz[j];
    float Xi = X[i], Xj = X[j], Yi = Y[i], Yj = Y[j];
    float sbij = sb[i * LL + j];
    double sum = (double)(si * sj) * (double)tS[ti];
    sum += (double)(Xi * Xj) * (double)tXX[ti];
    sum += (double)(Yi * Xj + Xi * Yj) * (double)tXY[ti];
    sum += (double)(Yi * Yj) * (double)tYY[ti];
    sum += (double)(si * sj * sbij) *
           ((double)tXe[ti] * (double)(Xi - Xj) + (double)tYe[ti] * (double)(Yi - Yj));
    if (i == j) {
        float ex = Xi - zx[0] * stx[i];
        float ey = Yi - zy[0] * sty[i];
        sum -= 0.5 * (double)xr[0] * ex * ex + 0.5 * (double)yr[0] * ey * ey;
    }
    red[tid] = sum; __syncthreads();
    for (int off = 128; off; off >>= 1) { if (tid < off) red[tid] += red[tid + off]; __syncthreads(); }
    if (tid == 0) atomicAdd(&acc[0], red[0]);
}

__global__ void finalize(const double* __restrict__ acc, float* __restrict__ out)
{
    out[0] = (float)(acc[0] + acc[1]);
}

// ---------------------------------------------------------------------------
extern "C" void kernel_launch(void* const* d_in, const int* in_sizes, int n_in,
                              void* d_out, int out_size, void* d_ws, size_t ws_size,
                              hipStream_t stream)
{
    const int*   occ  = (const int*)  d_in[0];
    const float* Sz   = (const float*)d_in[2];
    const float* X    = (const float*)d_in[3];
    const float* Y    = (const float*)d_in[4];
    const float* hv   = (const float*)d_in[5];
    const float* sv   = (const float*)d_in[6];
    const float* dv   = (const float*)d_in[7];
    const float* Jsp  = (const float*)d_in[8];
    const float* JXel = (const float*)d_in[9];
    const float* JYel = (const float*)d_in[10];
    const float* pXX  = (const float*)d_in[11];
    const float* pXY  = (const float*)d_in[12];
    const float* pYY  = (const float*)d_in[13];
    const float* g    = (const float*)d_in[14];
    const float* fS   = (const float*)d_in[15];
    const float* fd   = (const float*)d_in[16];
    const float* zx   = (const float*)d_in[17];
    const float* zy   = (const float*)d_in[18];
    const float* xr   = (const float*)d_in[19];
    const float* yr   = (const float*)d_in[20];
    const float* hop  = (const float*)d_in[21];
    const float* swm  = (const float*)d_in[22];
    const float* dwm  = (const float*)d_in[23];
    const int*   ivic = (const int*)  d_in[24];
    const float* sb   = (const float*)d_in[25];
    const float* stx  = (const float*)d_in[26];
    const float* sty  = (const float*)d_in[27];
    float* out = (float*)d_out;

    char* ws = (char*)d_ws;
    float*  W    = (float*) (ws + 0);           // 16.78 MB
    float*  v0   = (float*) (ws + 16777216);    // 8 KB
    float*  v1   = (float*) (ws + 16785408);    // 4 KB used
    int*    flags= (int*)   (ws + 16789504);    // 128 B
    float*  sig2 = (float*) (ws + 16793600);
    int*    sel  = (int*)   (ws + 16801792);
    float*  Mt   = (float*) (ws + 16805888);    // 4 MB; first 512KB doubles as Vbuf during Jacobi
    double* G    = (double*)(ws + 21000192);    // 8 MB fp64 Gram; doubles as Gpart (fp32) during Jacobi
    double* acc  = (double*)(ws + 29388800);    // 32 doubles
    int*    gctl = (int*)   (ws + 29389056);    // [0]=gconv [1]=streak [2..65]=clean
    int*    bars = (int*)   (ws + 29389568);    // tree barrier: 10 x 32 ints (128B-spaced)
    float*  Vbuf  = Mt;
    float*  Gpart = (float*)G;

    hipMemsetAsync(acc, 0, 2048, stream);       // zeroes acc + gctl + bars
    build_H<<<NN * NN / 256, 256, 0, stream>>>(hop, swm, dwm, hv, sv, dv, X, Y,
                                               ivic, sb, g, fS, fd, W);
    powv_init<<<8, 256, 0, stream>>>(v0);
    for (int it = 0; it < PITER; ++it) {
        const float* vin = (it & 1) ? v1 : v0;
        float* vout = (it & 1) ? v0 : v1;
        matvec<<<NN, 256, 0, stream>>>(W, vin, vout, acc + 8 + it);
    }
    add_shift<<<8, 256, 0, stream>>>(W, acc);

    // single persistent kernel for all NSWB*63 Jacobi rounds
    jac_fused<<<512, 512, 0, stream>>>(W, Gpart, Vbuf, flags, gctl, bars);

    colnorms<<<NN, 256, 0, stream>>>(W, sig2);
    select_k<<<8, 256, 0, stream>>>(sig2, sel);
    gather_M<<<4096, 256, 0, stream>>>(W, sig2, sel, occ, Mt);
    gram<<<dim3(64, 64), 256, 0, stream>>>(Mt, G);

    for (int s = 0; s < 16; ++s) {
        int k0 = s * 64;
        chol_panel<<<1, 256, 0, stream>>>(G, k0, acc);
        int nrows = LL - k0 - 64;
        if (nrows > 0) {
            chol_trsm<<<nrows / 32, 256, 0, stream>>>(G, k0);
            chol_syrk<<<dim3(nrows / 64, nrows / 64), 256, 0, stream>>>(G, k0);
        }
    }

    pair_sums<<<4096, 256, 0, stream>>>(Sz, X, Y, Jsp, JXel, JYel, pXX, pXY, pYY,
                                        sb, stx, sty, zx, zy, xr, yr, acc);
    finalize<<<1, 1, 0, stream>>>(acc, out);
}

// Round 4
// 70161.432 us; speedup vs baseline: 2.0472x; 1.2461x over previous
//
#include <hip/hip_runtime.h>
#include <math.h>

#define NN 2048   // 2L
#define LL 1024   // L
#define NSWB 8    // blocked Jacobi sweeps
#define NROUNDS (NSWB * 63)
#define PITER 10  // power iterations for spectral radius
#define JTAU 1e-8f   // relative off^2 threshold (|apq|_rel < 1e-4 -> identity)
#define STREAK_FULL 2016   // 63 rounds x 32 pairs all-skip = one clean sweep

// gctl layout (ints, zeroed at launch): [0]=gconv [1]=streak [2..65]=clean[64]

// ---------------------------------------------------------------------------
__global__ void build_H(const float* __restrict__ hop,  const float* __restrict__ swm,
                        const float* __restrict__ dwm,  const float* __restrict__ hv,
                        const float* __restrict__ sv,   const float* __restrict__ dv,
                        const float* __restrict__ X,    const float* __restrict__ Y,
                        const int*   __restrict__ ivic, const float* __restrict__ sb,
                        const float* __restrict__ gg,   const float* __restrict__ fS,
                        const float* __restrict__ fd,   float* __restrict__ W)
{
    int idx = blockIdx.x * 256 + threadIdx.x;
    int r = idx >> 11, c = idx & (NN - 1);
    float hv0 = hv[0], hv1 = hv[1], sv0 = sv[0], dv0 = dv[0];
    float g0 = gg[0], fS0 = fS[0], fd0 = fd[0];

    float val = 0.f;
    #pragma unroll
    for (int t = 0; t < 2; ++t) {
        int rr = t ? c : r;
        int cc = t ? r : c;
        int e  = rr * NN + cc;
        float v = hv0 * hop[e] - hop[NN*NN + e] + hv1 * hop[2*NN*NN + e]
                + sv0 * swm[e] + dv0 * dwm[e];
        int i = rr & (LL - 1), j = cc & (LL - 1);
        float px = 0.f, py = 0.f;
        float s = sb[i * LL + j];
        int n0 = ivic[i*4+0], n1 = ivic[i*4+1], n2 = ivic[i*4+2], n3 = ivic[i*4+3];
        if (j == n1 || j == n3) px = (X[j] - X[i]) * s;
        if (j == n0 || j == n2) py = (Y[j] - Y[i]) * s;
        float P = px + py, Mm = px - py;
        bool rlo = rr < LL, clo = cc < LL;
        if (rlo && clo)        v += g0 * P;
        else if (!rlo && !clo) v -= g0 * P;
        else                   v += fS0 * P + fd0 * Mm;
        val += 0.5f * v;
    }
    W[idx] = val;
}

// --------------------- power iteration for spectral radius ------------------
__global__ void powv_init(float* v)
{
    int i = blockIdx.x * 256 + threadIdx.x;
    if (i < NN) {
        unsigned h = (unsigned)i * 2654435761u;
        h ^= h >> 13; h *= 2246822519u; h ^= h >> 16;
        v[i] = ((h >> 8) * (1.0f / 16777216.f)) - 0.5f;
    }
}

__global__ void matvec(const float* __restrict__ W, const float* __restrict__ vin,
                       float* __restrict__ vout, double* accslot)
{
    __shared__ float red[256];
    int row = blockIdx.x, tid = threadIdx.x;
    const float* wr = W + (size_t)row * NN;
    float s = 0.f;
    for (int j = tid; j < NN; j += 256) s += wr[j] * vin[j];
    red[tid] = s; __syncthreads();
    for (int off = 128; off; off >>= 1) { if (tid < off) red[tid] += red[tid + off]; __syncthreads(); }
    if (tid == 0) { float y = red[0]; vout[row] = y; atomicAdd(accslot, (double)y * (double)y); }
}

__global__ void add_shift(float* W, const double* acc)
{
    int i = blockIdx.x * 256 + threadIdx.x;
    if (i < NN) {
        double n1 = acc[8 + PITER - 1], n0 = acc[8 + PITER - 2];
        float rho = (float)sqrt(n1 / (n0 > 0.0 ? n0 : 1.0));
        W[(size_t)i * NN + i] += 1.45f * rho;
    }
}

// ------------------- blocked Jacobi: fused persistent kernel ----------------
__device__ __forceinline__ void pair_groups(int pair, int r, int& gp, int& gq)
{
    if (pair == 0) gp = 0;
    else { int t1 = pair - 1 + r; if (t1 >= 63) t1 -= 63; gp = 1 + t1; }
    int t2 = 62 - pair + r; if (t2 >= 63) t2 -= 63; gq = 1 + t2;
}

// Relaxed agent-scope atomics: compile to sc0+sc1 accesses that go to the
// shared coherence point (Infinity Cache). NO fences anywhere in the loop ->
// the compiler never emits buffer_wbl2/buffer_inv (whole-L2 writeback/
// invalidate), which was the ~50us/barrier cost in v2. Ordering is manual:
// s_waitcnt vmcnt(0) before each barrier arrival guarantees prior stores
// have COMPLETED at the IF$ before the arrival becomes visible.
__device__ __forceinline__ int  ald(const int* p)
{ return __hip_atomic_load(p, __ATOMIC_RELAXED, __HIP_MEMORY_SCOPE_AGENT); }
__device__ __forceinline__ void ast(int* p, int v)
{ __hip_atomic_store(p, v, __ATOMIC_RELAXED, __HIP_MEMORY_SCOPE_AGENT); }
__device__ __forceinline__ float afld(const float* p)
{ return __hip_atomic_load(p, __ATOMIC_RELAXED, __HIP_MEMORY_SCOPE_AGENT); }
__device__ __forceinline__ void afst(float* p, float v)
{ __hip_atomic_store(p, v, __ATOMIC_RELAXED, __HIP_MEMORY_SCOPE_AGENT); }

// global tree barrier, fence-free. bars words spaced 4KB apart.
__device__ __forceinline__ void gridbar(int* bars, int phase)
{
    __syncthreads();
    if (threadIdx.x == 0) {
        asm volatile("s_waitcnt vmcnt(0)" ::: "memory");
        int g = blockIdx.x & 7;
        int old = __hip_atomic_fetch_add(&bars[g * 1024], 1,
                      __ATOMIC_RELAXED, __HIP_MEMORY_SCOPE_AGENT);
        if (old == phase * 64 - 1) {                       // group leader
            int t = __hip_atomic_fetch_add(&bars[8 * 1024], 1,
                        __ATOMIC_RELAXED, __HIP_MEMORY_SCOPE_AGENT);
            if (t == phase * 8 - 1)                        // global last
                ast(&bars[9 * 1024], phase);
        }
        while (ald(&bars[9 * 1024]) < phase)
            __builtin_amdgcn_s_sleep(8);
        asm volatile("" ::: "memory");
    }
    __syncthreads();
}

// pair-local barrier (16 blocks), fence-free; counter-only, monotone.
__device__ __forceinline__ void pairbar(int* ctr, int tgt)
{
    __syncthreads();
    if (threadIdx.x == 0) {
        asm volatile("s_waitcnt vmcnt(0)" ::: "memory");
        __hip_atomic_fetch_add(ctr, 1, __ATOMIC_RELAXED, __HIP_MEMORY_SCOPE_AGENT);
        while (ald(ctr) < tgt)
            __builtin_amdgcn_s_sleep(2);
        asm volatile("" ::: "memory");
    }
    __syncthreads();
}

// One kernel for all NSWB*63 rounds, 512 blocks x 512 threads (2/CU by LDS).
// Per round, block (pair,chunk) = (bid>>4, bid&15):
//   A: stage own 64col x 128row W tile (IF$ atomic loads) -> TT; partial
//      Gram -> Gpart chunk (IF$ atomic stores)
//   [pair-local barrier: 16 chunks of this pair]
//   B: EVERY block redundantly reduces its pair's 16 Gpart chunks -> S and
//      runs the 63-iter solve (V in registers; deterministic => all 16 blocks
//      compute identical V). No Vbuf, no flags, nobody idles.
//   C: apply TT x V -> W own tile (IF$ atomic stores), TT reused from A.
//   [global barrier]; uniform convergence break on gctl[0].
__global__ __launch_bounds__(512, 4) void jac_fused(float* __restrict__ W,
                                                    float* __restrict__ Gpart,
                                                    int* __restrict__ gctl,
                                                    int* __restrict__ bars,
                                                    int* __restrict__ pbars)
{
    __shared__ float TT[64][132];   // A/C: 64-col x 128-row W tile
    __shared__ float S[64][65];     // B: pair Gram
    __shared__ float Vs[64][64];    // B->C: V tile
    __shared__ float csC[32], csS[32];
    __shared__ int   pk[32], qk[32];
    __shared__ int   active;
    __shared__ int   nact[2];

    const int tid   = threadIdx.x;
    const int bid   = blockIdx.x;
    const int gpair = bid >> 4, chunk = bid & 15;
    const int r0    = chunk * 128;
    const bool ldr  = (chunk == 0 && tid == 0);   // single writer for gctl
    int gphase = 0, pphase = 0;

    for (int rr = 0; rr < NROUNDS; ++rr) {
        int r = rr; while (r >= 63) r -= 63;
        int gp, gq; pair_groups(gpair, r, gp, gq);
        int c1 = ald(&gctl[2 + gp]);
        int c2 = ald(&gctl[2 + gq]);
        bool hint = (c1 >= 63 && c2 >= 63);

        // ---------------- phase A: stage + gram ----------------
        if (!hint) {
            for (int u = tid; u < 8192; u += 512) {
                int c = u >> 7, row = u & 127;
                int col = (c < 32) ? gp * 32 + c : gq * 32 + (c - 32);
                TT[c][row] = afld(W + (size_t)col * NN + r0 + row);
            }
            __syncthreads();
            int tr = tid & 15, tc = tid >> 4;
            float acc[4][2] = {};
            for (int r4 = 0; r4 < 128; r4 += 4) {
                float a[4][4], b[2][4];
                #pragma unroll
                for (int m = 0; m < 4; ++m) *(float4*)a[m] = *(const float4*)&TT[tr + 16*m][r4];
                #pragma unroll
                for (int n = 0; n < 2; ++n) *(float4*)b[n] = *(const float4*)&TT[tc + 32*n][r4];
                #pragma unroll
                for (int m = 0; m < 4; ++m)
                    #pragma unroll
                    for (int n = 0; n < 2; ++n)
                        #pragma unroll
                        for (int k = 0; k < 4; ++k)
                            acc[m][n] += a[m][k] * b[n][k];
            }
            float* gout = Gpart + ((size_t)(gpair << 4) + chunk) * 4096;
            #pragma unroll
            for (int m = 0; m < 4; ++m)
                #pragma unroll
                for (int n = 0; n < 2; ++n)
                    afst(&gout[(tr + 16*m) * 64 + (tc + 32*n)], acc[m][n]);
            asm volatile("s_waitcnt vmcnt(0)" ::: "memory");
        }
        pairbar(&pbars[gpair * 1024], 16 * (++pphase));

        // ---------------- phase B: redundant solve ----------------
        int do_apply = 0;
        if (hint) {
            if (ldr) {
                ast(&gctl[2 + gp], c1 + 1);
                ast(&gctl[2 + gq], c2 + 1);
                int old = __hip_atomic_fetch_add(&gctl[1], 1,
                              __ATOMIC_RELAXED, __HIP_MEMORY_SCOPE_AGENT);
                if (old + 1 >= STREAK_FULL) ast(&gctl[0], 1);
            }
        } else {
            if (tid == 0) active = 0;
            if (tid < 2) nact[tid] = 0;
            for (int e = tid; e < 4096; e += 512) {
                float s = 0.f;
                #pragma unroll
                for (int ch = 0; ch < 16; ++ch)
                    s += afld(Gpart + ((size_t)(gpair * 16 + ch)) * 4096 + e);
                S[e >> 6][e & 63] = s;
            }
            __syncthreads();
            int loc = 0;
            for (int e = tid; e < 4096; e += 512) {
                int i = e >> 6, j = e & 63;
                if (i < j) {
                    float o = S[i][j];
                    if (o * o > JTAU * S[i][i] * S[j][j]) loc = 1;
                }
            }
            if (loc) active = 1;          // benign race: only ever set to 1
            __syncthreads();
            if (!active) {
                if (ldr) {
                    ast(&gctl[2 + gp], c1 + 1);
                    ast(&gctl[2 + gq], c2 + 1);
                    int old = __hip_atomic_fetch_add(&gctl[1], 1,
                                  __ATOMIC_RELAXED, __HIP_MEMORY_SCOPE_AGENT);
                    if (old + 1 >= STREAK_FULL) ast(&gctl[0], 1);
                }
            } else {
                do_apply = 1;
                if (ldr) {
                    ast(&gctl[2 + gp], 0);
                    ast(&gctl[2 + gq], 0);
                    __hip_atomic_exchange(&gctl[1], 0,
                        __ATOMIC_RELAXED, __HIP_MEMORY_SCOPE_AGENT);
                }
                int lane = tid & 63, wv = tid >> 6;   // 8 waves; wave w owns V rows 8w..8w+7
                float v[8];
                #pragma unroll
                for (int i = 0; i < 8; ++i) v[i] = (8 * wv + i == lane) ? 1.f : 0.f;

                for (int r2 = 0; r2 < 63; ++r2) {
                    if (tid < 32) {
                        int k = tid, p, q;
                        if (k == 0) p = 0;
                        else { int t1 = k - 1 + r2; if (t1 >= 63) t1 -= 63; p = 1 + t1; }
                        int t2 = 62 - k + r2; if (t2 >= 63) t2 -= 63; q = 1 + t2;
                        float app = S[p][p], aqq = S[q][q], apq = S[p][q];
                        float c = 1.f, s = 0.f;
                        if (apq * apq > JTAU * app * aqq) {
                            // fast-math chain (~1e-7 rel; Jacobi self-corrects)
                            float tau = (aqq - app) * __builtin_amdgcn_rcpf(2.f * apq);
                            float sq  = __builtin_amdgcn_sqrtf(fmaf(tau, tau, 1.f));
                            float t   = (tau >= 0.f ? 1.f : -1.f) *
                                        __builtin_amdgcn_rcpf(fabsf(tau) + sq);
                            c = __builtin_amdgcn_rsqf(fmaf(t, t, 1.f));
                            s = t * c;
                            nact[r2 & 1] = 1;     // benign multi-writer, same value
                        }
                        csC[k] = c; csS[k] = s; pk[k] = p; qk[k] = q;
                    }
                    if (tid == 256) nact[(r2 + 1) & 1] = 0;
                    __syncthreads();
                    if (!nact[r2 & 1]) break;
                    // one-pass S <- J^T S J over disjoint 2x2 blocks (2/thread)
                    for (int u = tid; u < 1024; u += 512) {
                        int ki = u >> 5, kj = u & 31;
                        float si_ = csS[ki], sj_ = csS[kj];
                        if (si_ == 0.f && sj_ == 0.f) continue;
                        float ci_ = csC[ki], cj_ = csC[kj];
                        int pi = pk[ki], qi = qk[ki], pj = pk[kj], qj = qk[kj];
                        float a  = S[pi][pj], b  = S[pi][qj];
                        float c2 = S[qi][pj], d  = S[qi][qj];
                        float a1 = cj_ * a  - sj_ * b,  b1 = sj_ * a  + cj_ * b;
                        float c1 = cj_ * c2 - sj_ * d,  d1 = sj_ * c2 + cj_ * d;
                        S[pi][pj] = ci_ * a1 - si_ * c1;
                        S[qi][pj] = si_ * a1 + ci_ * c1;
                        S[pi][qj] = ci_ * b1 - si_ * d1;
                        S[qi][qj] = si_ * b1 + ci_ * d1;
                    }
                    // V <- V * J (register resident: lane = column, shfl p<->q)
                    {
                        int k;
                        if (lane == 0) k = 0;
                        else { int t = lane - 1 - r2; if (t < 0) t += 63;
                               k = (t <= 30) ? (t + 1) : (62 - t); }
                        float s_ = csS[k];
                        if (s_ != 0.f) {
                            float c_ = csC[k];
                            int p = pk[k], q = qk[k];
                            bool isp = (lane == p);
                            int part = isp ? q : p;
                            #pragma unroll
                            for (int i = 0; i < 8; ++i) {
                                float other = __shfl(v[i], part);
                                v[i] = isp ? (c_ * v[i] - s_ * other)
                                           : (s_ * other + c_ * v[i]);
                            }
                        }
                    }
                    __syncthreads();
                }
                #pragma unroll
                for (int i = 0; i < 8; ++i) Vs[8 * wv + i][lane] = v[i];
                __syncthreads();
            }
        }

        // ---------------- phase C: apply (TT from A, Vs from B) -------------
        if (do_apply) {
            int rt = tid & 31, ct = tid >> 5;
            int rr0 = rt << 2, c20 = ct << 2;
            float acc[4][4] = {};
            for (int c = 0; c < 64; ++c) {
                float a[4], b[4];
                *(float4*)a = *(const float4*)&TT[c][rr0];
                *(float4*)b = *(const float4*)&Vs[c][c20];
                #pragma unroll
                for (int i = 0; i < 4; ++i)
                    #pragma unroll
                    for (int j = 0; j < 4; ++j)
                        acc[i][j] += a[i] * b[j];
            }
            __syncthreads();           // everyone done reading TT
            #pragma unroll
            for (int j = 0; j < 4; ++j)
                #pragma unroll
                for (int i = 0; i < 4; ++i)
                    TT[c20 + j][rr0 + i] = acc[i][j];
            __syncthreads();
            for (int u = tid; u < 8192; u += 512) {
                int c = u >> 7, row = u & 127;
                int col = (c < 32) ? gp * 32 + c : gq * 32 + (c - 32);
                afst(W + (size_t)col * NN + r0 + row, TT[c][row]);
            }
            asm volatile("s_waitcnt vmcnt(0)" ::: "memory");
        }
        gridbar(bars, ++gphase);
        if (ald(&gctl[0])) break;
    }
}

// --------------------- norms, selection, gather -----------------------------
__global__ void colnorms(const float* __restrict__ W, float* __restrict__ sig2)
{
    __shared__ float red[256];
    int col = blockIdx.x, tid = threadIdx.x;
    const float* c = W + (size_t)col * NN;
    float s = 0.f;
    for (int e = tid; e < NN; e += 256) s += c[e] * c[e];
    red[tid] = s; __syncthreads();
    for (int off = 128; off; off >>= 1) { if (tid < off) red[tid] += red[tid + off]; __syncthreads(); }
    if (tid == 0) sig2[col] = red[0];
}

__global__ void select_k(const float* __restrict__ sig2, int* __restrict__ sel)
{
    int i = blockIdx.x * 256 + threadIdx.x;
    if (i >= NN) return;
    float di = sig2[i]; int rank = 0;
    for (int j = 0; j < NN; ++j) {
        float dj = sig2[j];
        rank += (dj < di) || (dj == di && j < i);
    }
    if (rank < LL) sel[rank] = i;
}

__global__ void gather_M(const float* __restrict__ W, const float* __restrict__ sig2,
                         const int* __restrict__ sel, const int* __restrict__ occ,
                         float* __restrict__ Mt)
{
    int idx = blockIdx.x * 256 + threadIdx.x;
    int b = idx >> 10, a = idx & (LL - 1);
    int col = sel[b];
    float rn = 1.f / sqrtf(sig2[col]);
    Mt[(size_t)b * LL + a] = W[(size_t)col * NN + occ[a]] * rn;
}

// G = Mt^T * Mt in fp64 (= M M^T)
__global__ void gram(const float* __restrict__ Mt, double* __restrict__ G)
{
    __shared__ float As[32][17], Bs[32][17];
    int t = threadIdx.x;
    int tx = t & 15, ty = t >> 4;
    int a0 = blockIdx.y * 16, c0 = blockIdx.x * 16;
    double s = 0.0;
    for (int kb = 0; kb < LL; kb += 32) {
        for (int u = t; u < 32 * 16; u += 256) {
            int kr = u >> 4, i = u & 15;
            As[kr][i] = Mt[(size_t)(kb + kr) * LL + a0 + i];
            Bs[kr][i] = Mt[(size_t)(kb + kr) * LL + c0 + i];
        }
        __syncthreads();
        #pragma unroll 8
        for (int k2 = 0; k2 < 32; ++k2)
            s += (double)As[k2][ty] * (double)Bs[k2][tx];
        __syncthreads();
    }
    G[(size_t)(a0 + ty) * LL + (c0 + tx)] = s;
}

// --------------------- blocked fp64 Cholesky (panel 64) ---------------------
__global__ void chol_panel(double* __restrict__ G, int k0, double* __restrict__ acc)
{
    __shared__ double Ld[64][65];
    __shared__ double sinv;
    int tid = threadIdx.x;
    for (int u = tid; u < 4096; u += 256)
        Ld[u >> 6][u & 63] = G[(size_t)(k0 + (u >> 6)) * LL + k0 + (u & 63)];
    __syncthreads();
    double lsum = 0.0;
    for (int c = 0; c < 64; ++c) {
        if (tid == 0) {
            double d = Ld[c][c]; d = d > 1e-300 ? d : 1e-300;
            double sd = sqrt(d); lsum += log(sd);
            Ld[c][c] = sd; sinv = 1.0 / sd;
        }
        __syncthreads();
        if (tid < 63 - c) Ld[c + 1 + tid][c] *= sinv;
        __syncthreads();
        for (int u = tid; u < 4096; u += 256) {
            int rr = u >> 6, cc = u & 63;
            if (rr > c && cc > c) Ld[rr][cc] -= Ld[rr][c] * Ld[cc][c];
        }
        __syncthreads();
    }
    for (int u = tid; u < 4096; u += 256)
        G[(size_t)(k0 + (u >> 6)) * LL + k0 + (u & 63)] = Ld[u >> 6][u & 63];
    if (tid == 0) atomicAdd(acc + 1, lsum);
}

__global__ void chol_trsm(double* __restrict__ G, int k0)
{
    __shared__ double L11[64][65];
    __shared__ double Rt[32][65];
    int tid = threadIdx.x;
    int rbase = k0 + 64 + blockIdx.x * 32;
    for (int u = tid; u < 4096; u += 256)
        L11[u >> 6][u & 63] = G[(size_t)(k0 + (u >> 6)) * LL + k0 + (u & 63)];
    for (int u = tid; u < 2048; u += 256)
        Rt[u >> 6][u & 63] = G[(size_t)(rbase + (u >> 6)) * LL + k0 + (u & 63)];
    __syncthreads();
    for (int c = 0; c < 64; ++c) {
        if (tid < 32) Rt[tid][c] *= 1.0 / L11[c][c];
        __syncthreads();
        for (int u = tid; u < 2048; u += 256) {
            int rr = u >> 6, cc = u & 63;
            if (cc > c) Rt[rr][cc] -= Rt[rr][c] * L11[cc][c];
        }
        __syncthreads();
    }
    for (int u = tid; u < 2048; u += 256)
        G[(size_t)(rbase + (u >> 6)) * LL + k0 + (u & 63)] = Rt[u >> 6][u & 63];
}

__global__ void chol_syrk(double* __restrict__ G, int k0)
{
    __shared__ double At[64][32];
    __shared__ double Bt[64][32];
    int tid = threadIdx.x;
    int r0g = k0 + 64 + blockIdx.y * 64;
    int c0g = k0 + 64 + blockIdx.x * 64;
    int i0 = (tid >> 4) << 2, j0 = (tid & 15) << 2;
    double acc[4][4] = {};
    for (int kh = 0; kh < 2; ++kh) {
        for (int u = tid; u < 2048; u += 256) {
            int i = u >> 5, c = u & 31;
            At[i][c] = G[(size_t)(r0g + i) * LL + k0 + kh * 32 + c];
            Bt[i][c] = G[(size_t)(c0g + i) * LL + k0 + kh * 32 + c];
        }
        __syncthreads();
        for (int c = 0; c < 32; ++c) {
            int cr = (c + tid) & 31;
            double a[4], b[4];
            #pragma unroll
            for (int i = 0; i < 4; ++i) a[i] = At[i0 + i][cr];
            #pragma unroll
            for (int j = 0; j < 4; ++j) b[j] = Bt[j0 + j][cr];
            #pragma unroll
            for (int i = 0; i < 4; ++i)
                #pragma unroll
                for (int j = 0; j < 4; ++j)
                    acc[i][j] += a[i] * b[j];
        }
        __syncthreads();
    }
    #pragma unroll
    for (int i = 0; i < 4; ++i)
        #pragma unroll
        for (int j = 0; j < 4; ++j) {
            size_t e = (size_t)(r0g + i0 + i) * LL + c0g + j0 + j;
            G[e] -= acc[i][j];
        }
}

// --------- all O(L^2) circulant quadratic forms + coherent terms ------------
__global__ void pair_sums(const float* __restrict__ Sz,  const float* __restrict__ X,
                          const float* __restrict__ Y,
                          const float* __restrict__ Jsp, const float* __restrict__ JXel,
                          const float* __restrict__ JYel,const float* __restrict__ pXX,
                          const float* __restrict__ pXY, const float* __restrict__ pYY,
                          const float* __restrict__ sb,  const float* __restrict__ stx,
                          const float* __restrict__ sty,
                          const float* __restrict__ zx,  const float* __restrict__ zy,
                          const float* __restrict__ xr,  const float* __restrict__ yr,
                          double* __restrict__ acc)
{
    __shared__ float tS[289], tXe[289], tYe[289], tXX[289], tXY[289], tYY[289];
    __shared__ double red[256];
    int tid = threadIdx.x;
    for (int u = tid; u < 289; u += 256) {
        tS[u]  = (u < 288) ? Jsp[u] : 0.f;
        tXX[u] = (u < 288) ? pXX[u] : 0.f;
        tXY[u] = (u < 288) ? pXY[u] : 0.f;
        tYY[u] = (u < 288) ? pYY[u] : 0.f;
        tXe[u] = (u >= 1 && u < 288) ? JXel[u - 1] : 0.f;
        tYe[u] = (u >= 1 && u < 288) ? JYel[u - 1] : 0.f;
    }
    __syncthreads();
    int idx = blockIdx.x * 256 + tid;
    int i = idx >> 10, j = idx & (LL - 1);
    int xi = i >> 5, yi = i & 31, xj = j >> 5, yj = j & 31;
    int dx = (xj - xi) & 31, dy = (yj - yi) & 31;
    int rx = (dx <= 16) ? dx : 32 - dx;
    int ry = (dy <= 16) ? dy : 32 - dy;
    int ti = rx * 17 + ry;
    float si = Sz[i], sj = Sz[j];
    float Xi = X[i], Xj = X[j], Yi = Y[i], Yj = Y[j];
    float sbij = sb[i * LL + j];
    double sum = (double)(si * sj) * (double)tS[ti];
    sum += (double)(Xi * Xj) * (double)tXX[ti];
    sum += (double)(Yi * Xj + Xi * Yj) * (double)tXY[ti];
    sum += (double)(Yi * Yj) * (double)tYY[ti];
    sum += (double)(si * sj * sbij) *
           ((double)tXe[ti] * (double)(Xi - Xj) + (double)tYe[ti] * (double)(Yi - Yj));
    if (i == j) {
        float ex = Xi - zx[0] * stx[i];
        float ey = Yi - zy[0] * sty[i];
        sum -= 0.5 * (double)xr[0] * ex * ex + 0.5 * (double)yr[0] * ey * ey;
    }
    red[tid] = sum; __syncthreads();
    for (int off = 128; off; off >>= 1) { if (tid < off) red[tid] += red[tid + off]; __syncthreads(); }
    if (tid == 0) atomicAdd(&acc[0], red[0]);
}

__global__ void finalize(const double* __restrict__ acc, float* __restrict__ out)
{
    out[0] = (float)(acc[0] + acc[1]);
}

// ---------------------------------------------------------------------------
extern "C" void kernel_launch(void* const* d_in, const int* in_sizes, int n_in,
                              void* d_out, int out_size, void* d_ws, size_t ws_size,
                              hipStream_t stream)
{
    const int*   occ  = (const int*)  d_in[0];
    const float* Sz   = (const float*)d_in[2];
    const float* X    = (const float*)d_in[3];
    const float* Y    = (const float*)d_in[4];
    const float* hv   = (const float*)d_in[5];
    const float* sv   = (const float*)d_in[6];
    const float* dv   = (const float*)d_in[7];
    const float* Jsp  = (const float*)d_in[8];
    const float* JXel = (const float*)d_in[9];
    const float* JYel = (const float*)d_in[10];
    const float* pXX  = (const float*)d_in[11];
    const float* pXY  = (const float*)d_in[12];
    const float* pYY  = (const float*)d_in[13];
    const float* g    = (const float*)d_in[14];
    const float* fS   = (const float*)d_in[15];
    const float* fd   = (const float*)d_in[16];
    const float* zx   = (const float*)d_in[17];
    const float* zy   = (const float*)d_in[18];
    const float* xr   = (const float*)d_in[19];
    const float* yr   = (const float*)d_in[20];
    const float* hop  = (const float*)d_in[21];
    const float* swm  = (const float*)d_in[22];
    const float* dwm  = (const float*)d_in[23];
    const int*   ivic = (const int*)  d_in[24];
    const float* sb   = (const float*)d_in[25];
    const float* stx  = (const float*)d_in[26];
    const float* sty  = (const float*)d_in[27];
    float* out = (float*)d_out;

    char* ws = (char*)d_ws;
    float*  W    = (float*) (ws + 0);           // 16.78 MB
    float*  v0   = (float*) (ws + 16777216);    // 8 KB
    float*  v1   = (float*) (ws + 16785408);    // 4 KB used
    float*  sig2 = (float*) (ws + 16793600);
    int*    sel  = (int*)   (ws + 16801792);
    float*  Mt   = (float*) (ws + 16805888);    // 4 MB; first 172KB doubles as barrier words during Jacobi
    double* G    = (double*)(ws + 21000192);    // 8 MB fp64 Gram; doubles as Gpart (fp32) during Jacobi
    double* acc  = (double*)(ws + 29388800);    // 32 doubles
    int*    gctl = (int*)   (ws + 29389056);    // [0]=gconv [1]=streak [2..65]=clean
    int*    bars  = (int*)  Mt;                 // global barrier: 10 x 4KB-spaced words
    int*    pbars = bars + 10 * 1024;           // pair barriers: 32 x 4KB-spaced words
    float*  Gpart = (float*)G;

    hipMemsetAsync(acc, 0, 768, stream);              // acc + gctl
    hipMemsetAsync(bars, 0, 42 * 4096, stream);       // barrier words
    build_H<<<NN * NN / 256, 256, 0, stream>>>(hop, swm, dwm, hv, sv, dv, X, Y,
                                               ivic, sb, g, fS, fd, W);
    powv_init<<<8, 256, 0, stream>>>(v0);
    for (int it = 0; it < PITER; ++it) {
        const float* vin = (it & 1) ? v1 : v0;
        float* vout = (it & 1) ? v0 : v1;
        matvec<<<NN, 256, 0, stream>>>(W, vin, vout, acc + 8 + it);
    }
    add_shift<<<8, 256, 0, stream>>>(W, acc);

    // single persistent kernel for all NSWB*63 Jacobi rounds
    jac_fused<<<512, 512, 0, stream>>>(W, Gpart, gctl, bars, pbars);

    colnorms<<<NN, 256, 0, stream>>>(W, sig2);
    select_k<<<8, 256, 0, stream>>>(sig2, sel);
    gather_M<<<4096, 256, 0, stream>>>(W, sig2, sel, occ, Mt);
    gram<<<dim3(64, 64), 256, 0, stream>>>(Mt, G);

    for (int s = 0; s < 16; ++s) {
        int k0 = s * 64;
        chol_panel<<<1, 256, 0, stream>>>(G, k0, acc);
        int nrows = LL - k0 - 64;
        if (nrows > 0) {
            chol_trsm<<<nrows / 32, 256, 0, stream>>>(G, k0);
            chol_syrk<<<dim3(nrows / 64, nrows / 64), 256, 0, stream>>>(G, k0);
        }
    }

    pair_sums<<<4096, 256, 0, stream>>>(Sz, X, Y, Jsp, JXel, JYel, pXX, pXY, pYY,
                                        sb, stx, sty, zx, zy, xr, yr, acc);
    finalize<<<1, 1, 0, stream>>>(acc, out);
}